// Round 5
// baseline (149.306 us; speedup 1.0000x reference)
//
#include <hip/hip_runtime.h>
#include <math.h>

#define BATCH 8
#define SEQ   4096
#define DM    128
#define DS    128
#define N2    4096   // complex FFT length (r2c half-size; conv length 8192)
#define NT    256
#define NTP   256

__device__ __forceinline__ float2 cmulf(float2 a, float2 b) {
    return make_float2(a.x * b.x - a.y * b.y, a.x * b.y + a.y * b.x);
}
__device__ __forceinline__ float2 caddf(float2 a, float2 b) { return make_float2(a.x + b.x, a.y + b.y); }
__device__ __forceinline__ float2 csubf(float2 a, float2 b) { return make_float2(a.x - b.x, a.y - b.y); }
__device__ __forceinline__ float2 conjf2(float2 a) { return make_float2(a.x, -a.y); }
__device__ __forceinline__ float2 cisf(float t) { float s, c; __sincosf(t, &s, &c); return make_float2(c, s); }

// octal-digit reversal of 12-bit index (involution): after 4 radix-8 DIF stages
// (Q=512,64,8,1) bin k sits at logical position octrev(k).
__device__ __forceinline__ int octrev(int k) {
    return ((k & 7) << 9) | (((k >> 3) & 7) << 6) | (((k >> 6) & 7) << 3) | ((k >> 9) & 7);
}
// LDS anti-conflict swizzle (bijection); keeps every stage at the 4-way b64 minimum
__device__ __forceinline__ int physi(int a) { return a ^ ((a >> 4) & 15); }

// ---------------- in-register DFT-8 (natural order in/out) ----------------
#define RC8 0.70710678f
__device__ __forceinline__ void dft8_fwd(const float2 x[8], float2 X[8]) {
    float2 t0=caddf(x[0],x[4]), t1=caddf(x[1],x[5]), t2=caddf(x[2],x[6]), t3=caddf(x[3],x[7]);
    float2 d0=csubf(x[0],x[4]), d1=csubf(x[1],x[5]), d2=csubf(x[2],x[6]), d3=csubf(x[3],x[7]);
    float2 u0=d0;
    float2 u1=make_float2(RC8*(d1.x+d1.y), RC8*(d1.y-d1.x));      // d1 * e^{-i pi/4}
    float2 u2=make_float2(d2.y, -d2.x);                            // d2 * -i
    float2 u3=make_float2(RC8*(d3.y-d3.x), -RC8*(d3.x+d3.y));      // d3 * e^{-3i pi/4}
    float2 s0=caddf(t0,t2), s1=csubf(t0,t2), s2=caddf(t1,t3), s3=csubf(t1,t3);
    float2 s3m=make_float2(s3.y,-s3.x);
    X[0]=caddf(s0,s2); X[4]=csubf(s0,s2); X[2]=caddf(s1,s3m); X[6]=csubf(s1,s3m);
    float2 q0=caddf(u0,u2), q1=csubf(u0,u2), q2=caddf(u1,u3), q3=csubf(u1,u3);
    float2 q3m=make_float2(q3.y,-q3.x);
    X[1]=caddf(q0,q2); X[5]=csubf(q0,q2); X[3]=caddf(q1,q3m); X[7]=csubf(q1,q3m);
}
__device__ __forceinline__ void dft8_inv(const float2 x[8], float2 X[8]) {
    float2 t0=caddf(x[0],x[4]), t1=caddf(x[1],x[5]), t2=caddf(x[2],x[6]), t3=caddf(x[3],x[7]);
    float2 d0=csubf(x[0],x[4]), d1=csubf(x[1],x[5]), d2=csubf(x[2],x[6]), d3=csubf(x[3],x[7]);
    float2 u0=d0;
    float2 u1=make_float2(RC8*(d1.x-d1.y), RC8*(d1.x+d1.y));      // d1 * e^{+i pi/4}
    float2 u2=make_float2(-d2.y, d2.x);                            // d2 * +i
    float2 u3=make_float2(-RC8*(d3.x+d3.y), RC8*(d3.x-d3.y));      // d3 * e^{+3i pi/4}
    float2 s0=caddf(t0,t2), s1=csubf(t0,t2), s2=caddf(t1,t3), s3=csubf(t1,t3);
    float2 s3p=make_float2(-s3.y,s3.x);
    X[0]=caddf(s0,s2); X[4]=csubf(s0,s2); X[2]=caddf(s1,s3p); X[6]=csubf(s1,s3p);
    float2 q0=caddf(u0,u2), q1=csubf(u0,u2), q2=caddf(u1,u3), q3=csubf(u1,u3);
    float2 q3p=make_float2(-q3.y,q3.x);
    X[1]=caddf(q0,q2); X[5]=csubf(q0,q2); X[3]=caddf(q1,q3p); X[7]=csubf(q1,q3p);
}

// twiddle chain w^1..w^7 from w1 (depth 3)
#define TW_CHAIN(w1) \
    float2 w2 = cmulf(w1, w1); float2 w4 = cmulf(w2, w2); float2 w3 = cmulf(w2, w1); \
    float2 w5 = cmulf(w4, w1); float2 w6 = cmulf(w4, w2); float2 w7 = cmulf(w4, w3);

// ---------------- LDS radix-8 stages (2 butterflies/thread, NT=256) ----------------
template<int Q>
__device__ __forceinline__ void stage8_fwd(float2* z, int t) {
#pragma unroll
    for (int h = 0; h < 2; ++h) {
        int idx = t + 256 * h;
        int j = idx & (Q - 1);
        int base = ((idx & ~(Q - 1)) << 3) | j;
        int adr[8];
        float2 x[8], X[8];
#pragma unroll
        for (int r = 0; r < 8; ++r) { adr[r] = physi(base + Q * r); x[r] = z[adr[r]]; }
        dft8_fwd(x, X);
        if (Q > 1) {
            float2 w1 = cisf(-(float)M_PI / (4.0f * (float)Q) * (float)j);
            TW_CHAIN(w1);
            X[1]=cmulf(X[1],w1); X[2]=cmulf(X[2],w2); X[3]=cmulf(X[3],w3); X[4]=cmulf(X[4],w4);
            X[5]=cmulf(X[5],w5); X[6]=cmulf(X[6],w6); X[7]=cmulf(X[7],w7);
        }
#pragma unroll
        for (int r = 0; r < 8; ++r) z[adr[r]] = X[r];
    }
}
template<int Q>
__device__ __forceinline__ void stage8_inv(float2* z, int t) {
#pragma unroll
    for (int h = 0; h < 2; ++h) {
        int idx = t + 256 * h;
        int j = idx & (Q - 1);
        int base = ((idx & ~(Q - 1)) << 3) | j;
        int adr[8];
        float2 x[8], X[8];
#pragma unroll
        for (int r = 0; r < 8; ++r) { adr[r] = physi(base + Q * r); x[r] = z[adr[r]]; }
        if (Q > 1) {
            float2 w1 = cisf((float)M_PI / (4.0f * (float)Q) * (float)j);
            TW_CHAIN(w1);
            x[1]=cmulf(x[1],w1); x[2]=cmulf(x[2],w2); x[3]=cmulf(x[3],w3); x[4]=cmulf(x[4],w4);
            x[5]=cmulf(x[5],w5); x[6]=cmulf(x[6],w6); x[7]=cmulf(x[7],w7);
        }
        dft8_inv(x, X);
#pragma unroll
        for (int r = 0; r < 8; ++r) z[adr[r]] = X[r];
    }
}

// fused global load + first fwd stage (Q=512); vrow has 2048 valid float2, upper half zero
__device__ __forceinline__ void fwd_first8(float2* z, const float2* __restrict__ vrow, int t) {
#pragma unroll
    for (int h = 0; h < 2; ++h) {
        int idx = t + 256 * h;
        float2 x[8], X[8];
#pragma unroll
        for (int r = 0; r < 4; ++r) x[r] = vrow[idx + 512 * r];
#pragma unroll
        for (int r = 4; r < 8; ++r) x[r] = make_float2(0.f, 0.f);
        dft8_fwd(x, X);
        float2 w1 = cisf(-(float)M_PI / 2048.0f * (float)idx);
        TW_CHAIN(w1);
        X[1]=cmulf(X[1],w1); X[2]=cmulf(X[2],w2); X[3]=cmulf(X[3],w3); X[4]=cmulf(X[4],w4);
        X[5]=cmulf(X[5],w5); X[6]=cmulf(X[6],w6); X[7]=cmulf(X[7],w7);
#pragma unroll
        for (int r = 0; r < 8; ++r) z[physi(idx + 512 * r)] = X[r];
    }
}

// ---------------- P/Q pair coefficients (validated R3/R4; verbatim) ----------------
__device__ __forceinline__ void pq_one(float2 Kk, float2 Kkp, float thk,
                                       float2 fap, float2 fbp,
                                       float2* P, float2* Q) {
    float2 e  = cisf(-thk);
    float2 fa = make_float2(0.5f * (1.f + e.y), -0.5f * e.x);
    float2 fb = make_float2(0.5f * (1.f - e.y),  0.5f * e.x);
    float2 ak = cmulf(Kk, fa), bk = cmulf(Kk, fb);
    float2 apv = cmulf(Kkp, fap), bpv = cmulf(Kkp, fbp);
    float2 g = make_float2(0.5f * (1.f + e.y), 0.5f * e.x);
    float2 h = make_float2(0.5f * (1.f - e.y), -0.5f * e.x);
    *P = caddf(cmulf(g, ak), cmulf(h, conjf2(bpv)));
    *Q = caddf(cmulf(g, bk), cmulf(h, conjf2(apv)));
}
__device__ __forceinline__ void pq_pair(float2 Kk, float2 Kkp, float thk, float thkp,
                                        float2* Pk, float2* Qk, float2* Pkp, float2* Qkp) {
    float2 e  = cisf(-thk);
    float2 ep = cisf(-thkp);
    float2 fa  = make_float2(0.5f * (1.f + e.y),  -0.5f * e.x);
    float2 fb  = make_float2(0.5f * (1.f - e.y),   0.5f * e.x);
    float2 fap = make_float2(0.5f * (1.f + ep.y), -0.5f * ep.x);
    float2 fbp = make_float2(0.5f * (1.f - ep.y),  0.5f * ep.x);
    pq_one(Kk,  Kkp, thk,  fap, fbp, Pk,  Qk);
    pq_one(Kkp, Kk,  thkp, fa,  fb,  Pkp, Qkp);
}

// ---------------- fused prep: transpose_xin (blocks 0..4095) || psum (4096..4351) || G (4352..4415)
__global__ void __launch_bounds__(NTP) prep_fused(
    const float* __restrict__ x, float* __restrict__ xt,
    const float* __restrict__ Lam, const float* __restrict__ logdt, float* __restrict__ Psum,
    const float* __restrict__ Cm, const float* __restrict__ Bm, float* __restrict__ GT) {
    int bid = blockIdx.x, t = threadIdx.x;
    if (bid < 4096) {
        __shared__ float tile[32][33];
        int l0 = (bid & 127) * 32, m0 = ((bid >> 7) & 3) * 32, b = bid >> 9;
        int tx = t & 31, ty = t >> 5;
#pragma unroll
        for (int r = 0; r < 4; ++r) {
            int l = l0 + ty + r * 8;
            tile[ty + r * 8][tx] = x[(size_t)b * SEQ * DM + (size_t)l * DM + m0 + tx];
        }
        __syncthreads();
#pragma unroll
        for (int r = 0; r < 4; ++r) {
            int m = m0 + ty + r * 8;
            xt[(size_t)b * DM * SEQ + (size_t)m * SEQ + l0 + tx] = tile[tx][ty + r * 8];
        }
    } else if (bid < 4352) {
        __shared__ float E[DM];
        int sb = bid - 4096;
        int s = sb >> 1, half = sb & 1;
        if (t < DM) E[t] = __expf(logdt[t]) * Lam[s];
        __syncthreads();
        int l0 = t + 2048 * half;
        float acc[8] = {0.f,0.f,0.f,0.f,0.f,0.f,0.f,0.f};
        for (int m = 0; m < DM; ++m) {
            float e = E[m];
            float w = __expf(e * (float)l0);
            float r = __expf(e * 256.0f);
#pragma unroll
            for (int i = 0; i < 8; ++i) { acc[i] += w; w *= r; }
        }
#pragma unroll
        for (int i = 0; i < 8; ++i) Psum[s * SEQ + l0 + 256 * i] = acc[i];
    } else {
        int gid = (bid - 4352) * NTP + t;
        int m = gid >> 7, j = gid & 127;
        float acc = 0.f;
        for (int i = 0; i < DS; ++i) acc += Cm[m * DS + i] * Bm[i * DM + j];
        GT[j * DM + m] = acc;   // transposed for prep_K2
    }
}

// K[m,l] = sum_s GT[s,m]*Psum[s,l]; 16-wide l tile staged in LDS once (from R4, passed)
__global__ void prep_K2(const float* __restrict__ GT, const float* __restrict__ Psum,
                        float* __restrict__ K) {
    __shared__ float4 PT[DS][4];
    int l0 = blockIdx.x * 16;
    int t = threadIdx.x;
    for (int idx = t; idx < 512; idx += NTP) {
        int s = idx >> 2, q = idx & 3;
        PT[s][q] = ((const float4*)(Psum + s * SEQ + l0))[q];
    }
    __syncthreads();
    int m = t & 127, half = t >> 7;
    float acc[8] = {0.f,0.f,0.f,0.f,0.f,0.f,0.f,0.f};
    for (int s = 0; s < DS; ++s) {
        float g = GT[s * DM + m];
        float4 p0 = PT[s][half * 2], p1 = PT[s][half * 2 + 1];
        acc[0] += g * p0.x; acc[1] += g * p0.y; acc[2] += g * p0.z; acc[3] += g * p0.w;
        acc[4] += g * p1.x; acc[5] += g * p1.y; acc[6] += g * p1.z; acc[7] += g * p1.w;
    }
    float4* kp = (float4*)(K + (size_t)m * SEQ + l0 + half * 8);
    kp[0] = make_float4(acc[0], acc[1], acc[2], acc[3]);
    kp[1] = make_float4(acc[4], acc[5], acc[6], acc[7]);
}

// ---------------- fused: FFT of K row + Hermitian unpack + P/Q build ----------------
__global__ void __launch_bounds__(NT, 4) fftK_PQ(const float* __restrict__ K,
                                                 float4* __restrict__ PQ) {
    __shared__ __align__(16) float2 z[N2];
    int t = threadIdx.x, m = blockIdx.x;
    const float2* krow = (const float2*)(K + (size_t)m * SEQ);

    fwd_first8(z, krow, t); __syncthreads();
    stage8_fwd<64>(z, t);   __syncthreads();
    stage8_fwd<8>(z, t);    __syncthreads();
    stage8_fwd<1>(z, t);    __syncthreads();

    float4* dst = PQ + (size_t)m * 4096;
#pragma unroll
    for (int c = 0; c < 8; ++c) {
        int slot = (c << 8) | t;
        int k = (t << 3) | c;
        float2 Pk, Qk, Pkp, Qkp;
        if (k == 0) {
            float2 v0 = z[0];                       // pos(0)=0
            float2 v2 = z[4];                       // pos(2048)=octrev(2048)=4, physi(4)=4
            float2 Ku0    = make_float2(v0.x + v0.y, 0.f);
            float2 Ku4096 = make_float2(v0.x - v0.y, 0.f);
            float2 Ku2048 = conjf2(v2);
            float2 Pd, Qd;
            pq_pair(Ku0, Ku4096, 0.f, (float)M_PI, &Pk, &Qk, &Pd, &Qd);
            float th2 = 0.5f * (float)M_PI;
            pq_pair(Ku2048, Ku2048, th2, th2, &Pkp, &Qkp, &Pd, &Qd);
        } else {
            int kp = 4096 - k;
            float2 va = z[physi(octrev(k))];
            float2 vb = z[physi(octrev(kp))];
            float thk  = (float)M_PI * (float)k / 4096.0f;
            float thkp = (float)M_PI - thk;
            float2 e  = cisf(-thk);
            float2 cb = conjf2(vb);
            float2 s  = caddf(va, cb), d = csubf(va, cb);
            float2 pr = cmulf(e, d);
            float2 Kuk = make_float2(0.5f * (s.x + pr.y), 0.5f * (s.y - pr.x));
            float2 ep = make_float2(-e.x, e.y);
            float2 ca = conjf2(va);
            float2 s2 = caddf(vb, ca), d2 = csubf(vb, ca);
            float2 p2 = cmulf(ep, d2);
            float2 Kukp = make_float2(0.5f * (s2.x + p2.y), 0.5f * (s2.y - p2.x));
            pq_pair(Kuk, Kukp, thk, thkp, &Pk, &Qk, &Pkp, &Qkp);
        }
        dst[2 * slot]     = make_float4(Pk.x, Pk.y, Qk.x, Qk.y);
        dst[2 * slot + 1] = make_float4(Pkp.x, Pkp.y, Qkp.x, Qkp.y);
    }
}

// ---------------- main convolution (radix-8, no-spill) ----------------
__global__ void __launch_bounds__(NT, 4) conv8(float* __restrict__ xt,
                                               const float4* __restrict__ PQ,
                                               const float* __restrict__ Dv) {
    __shared__ __align__(16) float2 z[N2];
    int t = threadIdx.x;
    int m = blockIdx.x & (DM - 1);
    int b = blockIdx.x >> 7;
    float2* xrow = (float2*)(xt + (((size_t)b * DM + m) << 12));

    fwd_first8(z, xrow, t); __syncthreads();
    stage8_fwd<64>(z, t);   __syncthreads();
    stage8_fwd<8>(z, t);    __syncthreads();
    stage8_fwd<1>(z, t);    __syncthreads();

    // pointwise: W = P*V + Q*conj(V[partner]); one thread per pair, no inner barrier
    {
        const float4* pq = PQ + (size_t)m * 4096;
#pragma unroll
        for (int c = 0; c < 8; ++c) {
            int slot = (c << 8) | t;
            int k = (t << 3) | c;
            float4 lo = pq[2 * slot];
            float4 hi = pq[2 * slot + 1];
            if (k == 0) {
                float2 v0 = z[0];
                z[0] = caddf(cmulf(make_float2(lo.x, lo.y), v0),
                             cmulf(make_float2(lo.z, lo.w), conjf2(v0)));
                float2 v2 = z[4];
                z[4] = caddf(cmulf(make_float2(hi.x, hi.y), v2),
                             cmulf(make_float2(hi.z, hi.w), conjf2(v2)));
            } else {
                int i  = physi(octrev(k));
                int ip = physi(octrev(4096 - k));
                float2 va = z[i], vb = z[ip];
                z[i]  = caddf(cmulf(make_float2(lo.x, lo.y), va),
                              cmulf(make_float2(lo.z, lo.w), conjf2(vb)));
                z[ip] = caddf(cmulf(make_float2(hi.x, hi.y), vb),
                              cmulf(make_float2(hi.z, hi.w), conjf2(va)));
            }
        }
    }
    __syncthreads();

    stage8_inv<1>(z, t);    __syncthreads();
    stage8_inv<8>(z, t);    __syncthreads();
    stage8_inv<64>(z, t);   __syncthreads();

    // fused last inverse stage (Q=512) + normalize + skip + store (only n<2048 needed)
    {
        const float invN = 1.0f / 4096.0f;
        float dv = Dv[m];
#pragma unroll
        for (int h = 0; h < 2; ++h) {
            int idx = t + 256 * h;
            float2 y[8], D[8];
            float2 w1 = cisf((float)M_PI / 2048.0f * (float)idx);
            TW_CHAIN(w1);
            y[0] = z[physi(idx)];
            y[1] = cmulf(z[physi(idx + 512)],  w1);
            y[2] = cmulf(z[physi(idx + 1024)], w2);
            y[3] = cmulf(z[physi(idx + 1536)], w3);
            y[4] = cmulf(z[physi(idx + 2048)], w4);
            y[5] = cmulf(z[physi(idx + 2560)], w5);
            y[6] = cmulf(z[physi(idx + 3072)], w6);
            y[7] = cmulf(z[physi(idx + 3584)], w7);
            dft8_inv(y, D);
#pragma unroll
            for (int r = 0; r < 4; ++r) {
                int n = idx + 512 * r;
                float2 xv = xrow[n];
                xrow[n] = make_float2(D[r].x * invN + dv * xv.x, D[r].y * invN + dv * xv.y);
            }
        }
    }
}

// ---------------- output transpose ----------------
__global__ void transpose_yout(const float* __restrict__ yt, float* __restrict__ out) {
    __shared__ float tile[32][33];
    int b = blockIdx.z;
    int l0 = blockIdx.x * 32, m0 = blockIdx.y * 32;
    int tx = threadIdx.x, ty = threadIdx.y;
#pragma unroll
    for (int r = 0; r < 4; ++r) {
        int m = m0 + ty + r * 8;
        tile[ty + r * 8][tx] = yt[(size_t)b * DM * SEQ + (size_t)m * SEQ + l0 + tx];
    }
    __syncthreads();
#pragma unroll
    for (int r = 0; r < 4; ++r) {
        int l = l0 + ty + r * 8;
        out[(size_t)b * SEQ * DM + (size_t)l * DM + m0 + tx] = tile[tx][ty + r * 8];
    }
}

extern "C" void kernel_launch(void* const* d_in, const int* in_sizes, int n_in,
                              void* d_out, int out_size, void* d_ws, size_t ws_size,
                              hipStream_t stream) {
    const float* x     = (const float*)d_in[0];
    const float* Lam   = (const float*)d_in[1];
    const float* Bm    = (const float*)d_in[2];
    const float* Cm    = (const float*)d_in[3];
    const float* Dv    = (const float*)d_in[4];
    const float* logdt = (const float*)d_in[5];
    float* out = (float*)d_out;

    float*  ws   = (float*)d_ws;
    float*  xt   = ws;                                   // 4,194,304 floats (16 MB)
    float4* PQ   = (float4*)(ws + 4194304);              // 128*2048*2 float4 (8 MB)
    float*  K    = ws + 4194304 + 2097152;               // 524,288 floats (2 MB)
    float*  Psum = K + 524288;                           // 524,288 floats (2 MB)
    float*  GT   = Psum + 524288;                        // 16,384 floats

    hipLaunchKernelGGL(prep_fused,     dim3(4416),       dim3(NTP),    0, stream,
                       x, xt, Lam, logdt, Psum, Cm, Bm, GT);
    hipLaunchKernelGGL(prep_K2,        dim3(256),        dim3(NTP),    0, stream, GT, Psum, K);
    hipLaunchKernelGGL(fftK_PQ,        dim3(128),        dim3(NT),     0, stream, K, PQ);
    hipLaunchKernelGGL(conv8,          dim3(1024),       dim3(NT),     0, stream, xt, PQ, Dv);
    hipLaunchKernelGGL(transpose_yout, dim3(128, 4, 8),  dim3(32, 8),  0, stream, xt, out);
}